// Round 1
// 1104.500 us; speedup vs baseline: 1.2291x; 1.2291x over previous
//
#include <hip/hip_runtime.h>

#define N_NODES 50000
#define N_EDGES 1600000
#define IN_DIM  128
#define D       64      // OUT_DIM
#define E_IN    32
#define E_OUT   32
#define SCAN_CHUNK 256
#define N_CHUNKS ((N_NODES + SCAN_CHUNK - 1) / SCAN_CHUNK)   // 196

// ---------------------------------------------------------------------------
// K1: per-node precompute.  z = h @ W_node  [N,64]
//     s1 = z @ W_attn[:64], s2 = z @ W_attn[64:128]
//     u  = z @ W_tonode[:64]                [N,64]
// ---------------------------------------------------------------------------
__global__ __launch_bounds__(256) void node_a_kernel(
    const float* __restrict__ h, const float* __restrict__ Wn,
    const float* __restrict__ Wa, const float* __restrict__ Wt,
    float* __restrict__ z, float* __restrict__ u,
    float* __restrict__ s1, float* __restrict__ s2)
{
    __shared__ float lWn[IN_DIM * D];   // 32 KB
    __shared__ float lWt1[D * D];       // 16 KB
    __shared__ float lWa[2 * D];
    __shared__ float lh[4][IN_DIM];
    __shared__ float lz[4][D];

    const int tid = threadIdx.x;
    for (int i = tid; i < IN_DIM * D; i += 256) lWn[i] = Wn[i];
    for (int i = tid; i < D * D; i += 256) lWt1[i] = Wt[i];
    if (tid < 2 * D) lWa[tid] = Wa[tid];
    __syncthreads();

    const int wid = tid >> 6;
    const int lane = tid & 63;
    const int nwaves = gridDim.x * 4;

    for (int n = blockIdx.x * 4 + wid; n < N_NODES; n += nwaves) {
        lh[wid][lane]      = h[(size_t)n * IN_DIM + lane];
        lh[wid][lane + 64] = h[(size_t)n * IN_DIM + 64 + lane];

        float acc = 0.f;
        #pragma unroll 8
        for (int k = 0; k < IN_DIM; ++k)
            acc = fmaf(lh[wid][k], lWn[k * D + lane], acc);
        z[(size_t)n * D + lane] = acc;
        lz[wid][lane] = acc;

        float p1 = acc * lWa[lane];
        float p2 = acc * lWa[D + lane];
        #pragma unroll
        for (int off = 32; off > 0; off >>= 1) {
            p1 += __shfl_xor(p1, off, 64);
            p2 += __shfl_xor(p2, off, 64);
        }
        if (lane == 0) { s1[n] = p1; s2[n] = p2; }

        float ua = 0.f;
        #pragma unroll 8
        for (int k = 0; k < D; ++k)
            ua = fmaf(lz[wid][k], lWt1[k * D + lane], ua);
        u[(size_t)n * D + lane] = ua;
    }
}

// ---------------------------------------------------------------------------
// CSR build: histogram -> exclusive scan (3 kernels) -> scatter permutation
// ---------------------------------------------------------------------------
__global__ __launch_bounds__(256) void hist_kernel(
    const int* __restrict__ dst, int* __restrict__ count)
{
    int i = blockIdx.x * 256 + threadIdx.x;
    const int stride = gridDim.x * 256;
    for (; i < N_EDGES; i += stride) atomicAdd(&count[dst[i]], 1);
}

__global__ __launch_bounds__(256) void scan_sum_kernel(
    const int* __restrict__ count, int* __restrict__ bsum)
{
    __shared__ int s[256];
    const int t = threadIdx.x;
    const int idx = blockIdx.x * 256 + t;
    s[t] = (idx < N_NODES) ? count[idx] : 0;
    __syncthreads();
    for (int off = 128; off > 0; off >>= 1) {
        if (t < off) s[t] += s[t + off];
        __syncthreads();
    }
    if (t == 0) bsum[blockIdx.x] = s[0];
}

__global__ __launch_bounds__(256) void scan_top_kernel(int* __restrict__ bsum)
{
    __shared__ int s[256];
    const int t = threadIdx.x;
    const int v = (t < N_CHUNKS) ? bsum[t] : 0;
    s[t] = v;
    __syncthreads();
    for (int off = 1; off < 256; off <<= 1) {
        int x = (t >= off) ? s[t - off] : 0;
        __syncthreads();
        s[t] += x;
        __syncthreads();
    }
    if (t < N_CHUNKS) bsum[t] = s[t] - v;   // exclusive of chunk sums
}

__global__ __launch_bounds__(256) void scan_local_kernel(
    const int* __restrict__ count, const int* __restrict__ bsum,
    int* __restrict__ offsets, int* __restrict__ cursor)
{
    __shared__ int s[256];
    const int t = threadIdx.x;
    const int idx = blockIdx.x * 256 + t;
    const int v = (idx < N_NODES) ? count[idx] : 0;
    s[t] = v;
    __syncthreads();
    for (int off = 1; off < 256; off <<= 1) {
        int x = (t >= off) ? s[t - off] : 0;
        __syncthreads();
        s[t] += x;
        __syncthreads();
    }
    if (idx < N_NODES) {
        int e = bsum[blockIdx.x] + s[t] - v;  // exclusive prefix
        offsets[idx] = e;
        cursor[idx]  = e;
    }
}

// ---------------------------------------------------------------------------
// Scatter + fused attention-logit pass (edge-parallel).
// Each thread owns one edge: computes ex = exp(leakyrelu(s1[src]+s2[dst]
// + ew . Wa3)) ONCE (instead of 64x redundantly in the segment walk) and
// writes it at the sorted position, so the segment walk reads it coalesced.
// ---------------------------------------------------------------------------
__global__ __launch_bounds__(256) void scatter_ex_kernel(
    const float* __restrict__ edge_w, const int* __restrict__ src,
    const int* __restrict__ dst, const float* __restrict__ Wa,
    const float* __restrict__ s1, const float* __restrict__ s2,
    int* __restrict__ cursor, int* __restrict__ pe, int* __restrict__ ps,
    float* __restrict__ exs)
{
    float wa[E_IN];
    #pragma unroll
    for (int k = 0; k < E_IN; ++k) wa[k] = Wa[2 * D + k];  // uniform -> SGPRs

    int i = blockIdx.x * 256 + threadIdx.x;
    const int stride = gridDim.x * 256;
    for (; i < N_EDGES; i += stride) {
        const int s = src[i];
        const int d = dst[i];
        float a = s1[s] + s2[d];
        const float4* r4 = (const float4*)(edge_w + (size_t)i * E_IN);
        #pragma unroll
        for (int qq = 0; qq < E_IN / 4; ++qq) {
            float4 v = r4[qq];
            a = fmaf(v.x, wa[4 * qq + 0], a);
            a = fmaf(v.y, wa[4 * qq + 1], a);
            a = fmaf(v.z, wa[4 * qq + 2], a);
            a = fmaf(v.w, wa[4 * qq + 3], a);
        }
        const float lk = (a > 0.f) ? a : 0.1f * a;
        const float ex = __expf(lk);
        const int pos = atomicAdd(&cursor[d], 1);
        pe[pos]  = i;
        ps[pos]  = s;
        exs[pos] = ex;
    }
}

// ---------------------------------------------------------------------------
// K2: sorted edge pass A + fused node finalize.
// Per edge the wave now does only:
//   g   += ex * u[src]          (1 fma/lane, coalesced 256B row)
//   r   += ex * ew[e]           (32-dim; two edges share the wave's halves)
//   den += ex                   (vector accumulate, reduced once per node)
// The Wt2 matmul is factored out of the edge loop:
//   h = (g + r @ Wt2) / den     (once per node)
// 4-edge manual unroll: 6 independent loads in flight per step.
// ---------------------------------------------------------------------------
__global__ __launch_bounds__(256) void edge_a_sorted_kernel(
    const float* __restrict__ edge_w,
    const int* __restrict__ pe, const int* __restrict__ ps,
    const float* __restrict__ exs,
    const int* __restrict__ offsets, const int* __restrict__ count,
    const float* __restrict__ Wt, const float* __restrict__ We,
    const float* __restrict__ u, const float* __restrict__ z,
    float* __restrict__ hout, float* __restrict__ p, float* __restrict__ q)
{
    __shared__ float lWE[D * 64];   // [j][l]: l<32 -> We1[j][l], else We2[j][l-32]
    __shared__ float lh[4][D];
    __shared__ float lrr[4][E_IN];
    const int tid = threadIdx.x;
    for (int i = tid; i < D * 64; i += 256) {
        int j = i >> 6, l = i & 63;
        lWE[i] = We[(j + ((l < 32) ? 0 : D)) * E_OUT + (l & 31)];
    }
    __syncthreads();

    const int wid = tid >> 6, lane = tid & 63;
    const int nwaves = gridDim.x * 4;

    float wt2r[E_IN];
    #pragma unroll
    for (int k = 0; k < E_IN; ++k)
        wt2r[k] = Wt[(D + k) * D + lane];   // lane j holds W_tonode[64+k][j]

    for (int n = blockIdx.x * 4 + wid; n < N_NODES; n += nwaves) {
        const int off = offsets[n];
        const int deg = count[n];
        float g = 0.f, rv = 0.f, denv = 0.f;

        for (int b = 0; b < deg; b += 64) {
            int rem = deg - b; if (rem > 64) rem = 64;
            int eb = 0, sb = 0; float exv = 0.f;
            if (lane < rem) {
                eb  = pe[off + b + lane];
                sb  = ps[off + b + lane];
                exv = exs[off + b + lane];
            }
            denv += exv;
            // lanes >= rem hold exv=0 and eb=sb=0 (valid addresses), so the
            // padded tail contributes exactly zero -> no guards needed.
            const int rem4 = (rem + 3) & ~3;
            for (int i = 0; i < rem4; i += 4) {
                const int s0 = __builtin_amdgcn_readlane(sb, i);
                const int s1 = __builtin_amdgcn_readlane(sb, i + 1);
                const int s2 = __builtin_amdgcn_readlane(sb, i + 2);
                const int s3 = __builtin_amdgcn_readlane(sb, i + 3);
                const int e0 = __builtin_amdgcn_readlane(eb, i);
                const int e1 = __builtin_amdgcn_readlane(eb, i + 1);
                const int e2 = __builtin_amdgcn_readlane(eb, i + 2);
                const int e3 = __builtin_amdgcn_readlane(eb, i + 3);
                const float x0 = __int_as_float(__builtin_amdgcn_readlane(__float_as_int(exv), i));
                const float x1 = __int_as_float(__builtin_amdgcn_readlane(__float_as_int(exv), i + 1));
                const float x2 = __int_as_float(__builtin_amdgcn_readlane(__float_as_int(exv), i + 2));
                const float x3 = __int_as_float(__builtin_amdgcn_readlane(__float_as_int(exv), i + 3));
                // 6 independent loads issued before any use
                const float u0 = u[(size_t)s0 * D + lane];
                const float u1 = u[(size_t)s1 * D + lane];
                const float u2 = u[(size_t)s2 * D + lane];
                const float u3 = u[(size_t)s3 * D + lane];
                const int   ea = (lane < 32) ? e0 : e1;
                const float xa = (lane < 32) ? x0 : x1;
                const int   ec = (lane < 32) ? e2 : e3;
                const float xc = (lane < 32) ? x2 : x3;
                const float w0 = edge_w[(size_t)ea * E_IN + (lane & 31)];
                const float w1 = edge_w[(size_t)ec * E_IN + (lane & 31)];
                g  = fmaf(x0, u0, g);
                g  = fmaf(x1, u1, g);
                g  = fmaf(x2, u2, g);
                g  = fmaf(x3, u3, g);
                rv = fmaf(xa, w0, rv);
                rv = fmaf(xc, w1, rv);
            }
        }

        // fold the two r-halves (even-slot edges in lanes 0-31, odd in 32-63)
        rv += __shfl_xor(rv, 32, 64);
        if (lane < 32) lrr[wid][lane] = rv;
        #pragma unroll
        for (int o = 32; o > 0; o >>= 1) denv += __shfl_xor(denv, o, 64);

        // h = (g + r @ Wt2) / den   (Wt2 matmul once per node, not per edge)
        float acc = g;
        #pragma unroll
        for (int k = 0; k < E_IN; ++k)
            acc = fmaf(lrr[wid][k], wt2r[k], acc);

        const float hv = (deg > 0) ? acc / denv : z[(size_t)n * D + lane];
        hout[(size_t)n * D + lane] = hv;
        lh[wid][lane] = hv;

        float pacc = 0.f;
        #pragma unroll 8
        for (int j = 0; j < D; ++j)
            pacc = fmaf(lh[wid][j], lWE[j * 64 + lane], pacc);

        float* o = (lane < 32) ? p : q;
        o[(size_t)n * E_OUT + (lane & 31)] = pacc;
    }
}

// ---------------------------------------------------------------------------
// K3: edge pass B. Two edges per wave, lane&31 owns an output column.
//   w = p[src] + q[dst] + ew @ W_edge[128:]
// ---------------------------------------------------------------------------
__global__ __launch_bounds__(256) void edge_b_kernel(
    const float* __restrict__ edge_w, const int* __restrict__ src,
    const int* __restrict__ dst, const float* __restrict__ We,
    const float* __restrict__ p, const float* __restrict__ q,
    float* __restrict__ wout)
{
    const int lane = threadIdx.x & 63;
    const int i = lane & 31;
    const int half = lane >> 5;
    const int wp0 = blockIdx.x * 4 + (threadIdx.x >> 6);
    const int npairs = N_EDGES / 2;
    const int nw = gridDim.x * 4;

    float we3r[E_IN];
    #pragma unroll
    for (int k = 0; k < E_IN; ++k) we3r[k] = We[(2 * D + k) * E_OUT + i];

    for (int wp = wp0; wp < npairs; wp += nw) {
        const int e = 2 * wp + half;
        const int s = src[e], d = dst[e];
        float acc = p[(size_t)s * E_OUT + i] + q[(size_t)d * E_OUT + i];
        const float4* ew4 = (const float4*)(edge_w + (size_t)e * E_IN);
        #pragma unroll
        for (int qq = 0; qq < E_IN / 4; ++qq) {
            float4 v = ew4[qq];
            acc = fmaf(v.x, we3r[4*qq+0], acc);
            acc = fmaf(v.y, we3r[4*qq+1], acc);
            acc = fmaf(v.z, we3r[4*qq+2], acc);
            acc = fmaf(v.w, we3r[4*qq+3], acc);
        }
        wout[(size_t)e * E_OUT + i] = acc;
    }
}

// ---------------------------------------------------------------------------
extern "C" void kernel_launch(void* const* d_in, const int* in_sizes, int n_in,
                              void* d_out, int out_size, void* d_ws, size_t ws_size,
                              hipStream_t stream) {
    const float* h  = (const float*)d_in[0];
    const float* ew = (const float*)d_in[1];
    const float* Wn = (const float*)d_in[2];
    const float* Wa = (const float*)d_in[3];
    const float* Wt = (const float*)d_in[4];
    const float* We = (const float*)d_in[5];
    const int* src  = (const int*)d_in[6];
    const int* dst  = (const int*)d_in[7];

    float* z    = (float*)d_ws;                       // N*64
    float* u    = z + (size_t)N_NODES * D;            // N*64
    float* s1   = u + (size_t)N_NODES * D;            // N
    float* s2   = s1 + N_NODES;                       // N
    float* p    = s2 + N_NODES;                       // N*32
    float* q    = p + (size_t)N_NODES * E_OUT;        // N*32
    int* counts = (int*)(q + (size_t)N_NODES * E_OUT);// N
    int* offs   = counts + N_NODES;                   // N
    int* cursor = offs + N_NODES;                     // N
    int* bsum   = cursor + N_NODES;                   // 256
    int* pe     = bsum + 256;                         // E
    int* ps     = pe + N_EDGES;                       // E
    float* exs  = (float*)(ps + N_EDGES);             // E

    float* hout = (float*)d_out;
    float* wout = hout + (size_t)N_NODES * D;

    hipMemsetAsync(counts, 0, N_NODES * sizeof(int), stream);

    node_a_kernel<<<1024, 256, 0, stream>>>(h, Wn, Wa, Wt, z, u, s1, s2);
    hist_kernel<<<1024, 256, 0, stream>>>(dst, counts);
    scan_sum_kernel<<<N_CHUNKS, 256, 0, stream>>>(counts, bsum);
    scan_top_kernel<<<1, 256, 0, stream>>>(bsum);
    scan_local_kernel<<<N_CHUNKS, 256, 0, stream>>>(counts, bsum, offs, cursor);
    scatter_ex_kernel<<<2048, 256, 0, stream>>>(ew, src, dst, Wa, s1, s2,
                                                cursor, pe, ps, exs);
    edge_a_sorted_kernel<<<2048, 256, 0, stream>>>(ew, pe, ps, exs, offs, counts,
                                                   Wt, We, u, z, hout, p, q);
    edge_b_kernel<<<2048, 256, 0, stream>>>(ew, src, dst, We, p, q, wout);
}

// Round 2
// 993.072 us; speedup vs baseline: 1.3670x; 1.1122x over previous
//
#include <hip/hip_runtime.h>

#define N_NODES 50000
#define N_EDGES 1600000
#define IN_DIM  128
#define D       64      // OUT_DIM
#define E_IN    32
#define E_OUT   32
#define SCAN_CHUNK 256
#define N_CHUNKS ((N_NODES + SCAN_CHUNK - 1) / SCAN_CHUNK)   // 196

typedef __attribute__((ext_vector_type(4))) float f32x4;

// ---------------------------------------------------------------------------
// K1: per-node precompute.  z = h @ W_node  [N,64]
//     s1 = z @ W_attn[:64], s2 = z @ W_attn[64:128]
//     u  = z @ W_tonode[:64]                [N,64]
// ---------------------------------------------------------------------------
__global__ __launch_bounds__(256) void node_a_kernel(
    const float* __restrict__ h, const float* __restrict__ Wn,
    const float* __restrict__ Wa, const float* __restrict__ Wt,
    float* __restrict__ z, float* __restrict__ u,
    float* __restrict__ s1, float* __restrict__ s2)
{
    __shared__ float lWn[IN_DIM * D];   // 32 KB
    __shared__ float lWt1[D * D];       // 16 KB
    __shared__ float lWa[2 * D];
    __shared__ float lh[4][IN_DIM];
    __shared__ float lz[4][D];

    const int tid = threadIdx.x;
    for (int i = tid; i < IN_DIM * D; i += 256) lWn[i] = Wn[i];
    for (int i = tid; i < D * D; i += 256) lWt1[i] = Wt[i];
    if (tid < 2 * D) lWa[tid] = Wa[tid];
    __syncthreads();

    const int wid = tid >> 6;
    const int lane = tid & 63;
    const int nwaves = gridDim.x * 4;

    for (int n = blockIdx.x * 4 + wid; n < N_NODES; n += nwaves) {
        lh[wid][lane]      = h[(size_t)n * IN_DIM + lane];
        lh[wid][lane + 64] = h[(size_t)n * IN_DIM + 64 + lane];

        float acc = 0.f;
        #pragma unroll 8
        for (int k = 0; k < IN_DIM; ++k)
            acc = fmaf(lh[wid][k], lWn[k * D + lane], acc);
        z[(size_t)n * D + lane] = acc;
        lz[wid][lane] = acc;

        float p1 = acc * lWa[lane];
        float p2 = acc * lWa[D + lane];
        #pragma unroll
        for (int off = 32; off > 0; off >>= 1) {
            p1 += __shfl_xor(p1, off, 64);
            p2 += __shfl_xor(p2, off, 64);
        }
        if (lane == 0) { s1[n] = p1; s2[n] = p2; }

        float ua = 0.f;
        #pragma unroll 8
        for (int k = 0; k < D; ++k)
            ua = fmaf(lz[wid][k], lWt1[k * D + lane], ua);
        u[(size_t)n * D + lane] = ua;
    }
}

// ---------------------------------------------------------------------------
// CSR build: histogram -> exclusive scan (3 kernels) -> scatter permutation
// ---------------------------------------------------------------------------
__global__ __launch_bounds__(256) void hist_kernel(
    const int* __restrict__ dst, int* __restrict__ count)
{
    int i = blockIdx.x * 256 + threadIdx.x;
    const int stride = gridDim.x * 256;
    for (; i < N_EDGES; i += stride) atomicAdd(&count[dst[i]], 1);
}

__global__ __launch_bounds__(256) void scan_sum_kernel(
    const int* __restrict__ count, int* __restrict__ bsum)
{
    __shared__ int s[256];
    const int t = threadIdx.x;
    const int idx = blockIdx.x * 256 + t;
    s[t] = (idx < N_NODES) ? count[idx] : 0;
    __syncthreads();
    for (int off = 128; off > 0; off >>= 1) {
        if (t < off) s[t] += s[t + off];
        __syncthreads();
    }
    if (t == 0) bsum[blockIdx.x] = s[0];
}

__global__ __launch_bounds__(256) void scan_top_kernel(int* __restrict__ bsum)
{
    __shared__ int s[256];
    const int t = threadIdx.x;
    const int v = (t < N_CHUNKS) ? bsum[t] : 0;
    s[t] = v;
    __syncthreads();
    for (int off = 1; off < 256; off <<= 1) {
        int x = (t >= off) ? s[t - off] : 0;
        __syncthreads();
        s[t] += x;
        __syncthreads();
    }
    if (t < N_CHUNKS) bsum[t] = s[t] - v;   // exclusive of chunk sums
}

__global__ __launch_bounds__(256) void scan_local_kernel(
    const int* __restrict__ count, const int* __restrict__ bsum,
    int* __restrict__ offsets, int* __restrict__ cursor)
{
    __shared__ int s[256];
    const int t = threadIdx.x;
    const int idx = blockIdx.x * 256 + t;
    const int v = (idx < N_NODES) ? count[idx] : 0;
    s[t] = v;
    __syncthreads();
    for (int off = 1; off < 256; off <<= 1) {
        int x = (t >= off) ? s[t - off] : 0;
        __syncthreads();
        s[t] += x;
        __syncthreads();
    }
    if (idx < N_NODES) {
        int e = bsum[blockIdx.x] + s[t] - v;  // exclusive prefix
        offsets[idx] = e;
        cursor[idx]  = e;
    }
}

// ---------------------------------------------------------------------------
// Scatter + fused attention-logit pass (edge-parallel).
// ---------------------------------------------------------------------------
__global__ __launch_bounds__(256) void scatter_ex_kernel(
    const float* __restrict__ edge_w, const int* __restrict__ src,
    const int* __restrict__ dst, const float* __restrict__ Wa,
    const float* __restrict__ s1, const float* __restrict__ s2,
    int* __restrict__ cursor, int* __restrict__ pe, int* __restrict__ ps,
    float* __restrict__ exs)
{
    float wa[E_IN];
    #pragma unroll
    for (int k = 0; k < E_IN; ++k) wa[k] = Wa[2 * D + k];  // uniform -> SGPRs

    int i = blockIdx.x * 256 + threadIdx.x;
    const int stride = gridDim.x * 256;
    for (; i < N_EDGES; i += stride) {
        const int s = src[i];
        const int d = dst[i];
        float a = s1[s] + s2[d];
        const float4* r4 = (const float4*)(edge_w + (size_t)i * E_IN);
        #pragma unroll
        for (int qq = 0; qq < E_IN / 4; ++qq) {
            float4 v = r4[qq];
            a = fmaf(v.x, wa[4 * qq + 0], a);
            a = fmaf(v.y, wa[4 * qq + 1], a);
            a = fmaf(v.z, wa[4 * qq + 2], a);
            a = fmaf(v.w, wa[4 * qq + 3], a);
        }
        const float lk = (a > 0.f) ? a : 0.1f * a;
        const float ex = __expf(lk);
        const int pos = atomicAdd(&cursor[d], 1);
        pe[pos]  = i;
        ps[pos]  = s;
        exs[pos] = ex;
    }
}

// ---------------------------------------------------------------------------
// K2: sorted edge pass A + fused node finalize (unchanged from round 1).
// ---------------------------------------------------------------------------
__global__ __launch_bounds__(256) void edge_a_sorted_kernel(
    const float* __restrict__ edge_w,
    const int* __restrict__ pe, const int* __restrict__ ps,
    const float* __restrict__ exs,
    const int* __restrict__ offsets, const int* __restrict__ count,
    const float* __restrict__ Wt, const float* __restrict__ We,
    const float* __restrict__ u, const float* __restrict__ z,
    float* __restrict__ hout, float* __restrict__ p, float* __restrict__ q)
{
    __shared__ float lWE[D * 64];   // [j][l]: l<32 -> We1[j][l], else We2[j][l-32]
    __shared__ float lh[4][D];
    __shared__ float lrr[4][E_IN];
    const int tid = threadIdx.x;
    for (int i = tid; i < D * 64; i += 256) {
        int j = i >> 6, l = i & 63;
        lWE[i] = We[(j + ((l < 32) ? 0 : D)) * E_OUT + (l & 31)];
    }
    __syncthreads();

    const int wid = tid >> 6, lane = tid & 63;
    const int nwaves = gridDim.x * 4;

    float wt2r[E_IN];
    #pragma unroll
    for (int k = 0; k < E_IN; ++k)
        wt2r[k] = Wt[(D + k) * D + lane];   // lane j holds W_tonode[64+k][j]

    for (int n = blockIdx.x * 4 + wid; n < N_NODES; n += nwaves) {
        const int off = offsets[n];
        const int deg = count[n];
        float g = 0.f, rv = 0.f, denv = 0.f;

        for (int b = 0; b < deg; b += 64) {
            int rem = deg - b; if (rem > 64) rem = 64;
            int eb = 0, sb = 0; float exv = 0.f;
            if (lane < rem) {
                eb  = pe[off + b + lane];
                sb  = ps[off + b + lane];
                exv = exs[off + b + lane];
            }
            denv += exv;
            const int rem4 = (rem + 3) & ~3;
            for (int i = 0; i < rem4; i += 4) {
                const int s0 = __builtin_amdgcn_readlane(sb, i);
                const int s1 = __builtin_amdgcn_readlane(sb, i + 1);
                const int s2 = __builtin_amdgcn_readlane(sb, i + 2);
                const int s3 = __builtin_amdgcn_readlane(sb, i + 3);
                const int e0 = __builtin_amdgcn_readlane(eb, i);
                const int e1 = __builtin_amdgcn_readlane(eb, i + 1);
                const int e2 = __builtin_amdgcn_readlane(eb, i + 2);
                const int e3 = __builtin_amdgcn_readlane(eb, i + 3);
                const float x0 = __int_as_float(__builtin_amdgcn_readlane(__float_as_int(exv), i));
                const float x1 = __int_as_float(__builtin_amdgcn_readlane(__float_as_int(exv), i + 1));
                const float x2 = __int_as_float(__builtin_amdgcn_readlane(__float_as_int(exv), i + 2));
                const float x3 = __int_as_float(__builtin_amdgcn_readlane(__float_as_int(exv), i + 3));
                const float u0 = u[(size_t)s0 * D + lane];
                const float u1 = u[(size_t)s1 * D + lane];
                const float u2 = u[(size_t)s2 * D + lane];
                const float u3 = u[(size_t)s3 * D + lane];
                const int   ea = (lane < 32) ? e0 : e1;
                const float xa = (lane < 32) ? x0 : x1;
                const int   ec = (lane < 32) ? e2 : e3;
                const float xc = (lane < 32) ? x2 : x3;
                const float w0 = edge_w[(size_t)ea * E_IN + (lane & 31)];
                const float w1 = edge_w[(size_t)ec * E_IN + (lane & 31)];
                g  = fmaf(x0, u0, g);
                g  = fmaf(x1, u1, g);
                g  = fmaf(x2, u2, g);
                g  = fmaf(x3, u3, g);
                rv = fmaf(xa, w0, rv);
                rv = fmaf(xc, w1, rv);
            }
        }

        rv += __shfl_xor(rv, 32, 64);
        if (lane < 32) lrr[wid][lane] = rv;
        #pragma unroll
        for (int o = 32; o > 0; o >>= 1) denv += __shfl_xor(denv, o, 64);

        float acc = g;
        #pragma unroll
        for (int k = 0; k < E_IN; ++k)
            acc = fmaf(lrr[wid][k], wt2r[k], acc);

        const float hv = (deg > 0) ? acc / denv : z[(size_t)n * D + lane];
        hout[(size_t)n * D + lane] = hv;
        lh[wid][lane] = hv;

        float pacc = 0.f;
        #pragma unroll 8
        for (int j = 0; j < D; ++j)
            pacc = fmaf(lh[wid][j], lWE[j * 64 + lane], pacc);

        float* o = (lane < 32) ? p : q;
        o[(size_t)n * E_OUT + (lane & 31)] = pacc;
    }
}

// ---------------------------------------------------------------------------
// K3: edge pass B — MLP-unrolled. 8 edges (4 pairs) per wave per iteration.
//   w[e] = p[src[e]] + q[dst[e]] + ew[e] @ We3
// All 8 index loads hoisted + prefetched one iteration ahead; all 8 p/q
// gathers issued back-to-back (8 independent chains in flight vs 2 before).
// ew reads and wout writes are nontemporal so the ~410 MB of streaming
// traffic doesn't evict the 12.8 MB p/q gather tables from L2.
// ---------------------------------------------------------------------------
__global__ __launch_bounds__(256) void edge_b_kernel(
    const float* __restrict__ edge_w, const int* __restrict__ src,
    const int* __restrict__ dst, const float* __restrict__ We,
    const float* __restrict__ p, const float* __restrict__ q,
    float* __restrict__ wout)
{
    const int lane = threadIdx.x & 63;
    const int ic   = lane & 31;
    const int half = lane >> 5;
    const int g0   = blockIdx.x * 4 + (threadIdx.x >> 6);
    const int ngroups = N_EDGES / 8;          // 200000 exactly
    const int nw   = gridDim.x * 4;

    float we3r[E_IN];
    #pragma unroll
    for (int k = 0; k < E_IN; ++k) we3r[k] = We[(2 * D + k) * E_OUT + ic];

    if (g0 >= ngroups) return;

    // prime the index pipeline
    int s[4], d[4];
    #pragma unroll
    for (int i = 0; i < 4; ++i) {
        const int e = g0 * 8 + 2 * i + half;
        s[i] = src[e];
        d[i] = dst[e];
    }

    for (int g = g0; g < ngroups; g += nw) {
        const int ebase = g * 8;
        const int gn = g + nw;

        // issue all 8 gathers immediately (independent chains)
        float pv[4], qv[4];
        #pragma unroll
        for (int i = 0; i < 4; ++i) pv[i] = p[(size_t)s[i] * E_OUT + ic];
        #pragma unroll
        for (int i = 0; i < 4; ++i) qv[i] = q[(size_t)d[i] * E_OUT + ic];

        // prefetch next iteration's indices (hides idx->gather serial dep)
        if (gn < ngroups) {
            #pragma unroll
            for (int i = 0; i < 4; ++i) {
                const int e = gn * 8 + 2 * i + half;
                s[i] = src[e];
                d[i] = dst[e];
            }
        }

        // ew @ We3 while the gathers are in flight
        float acc[4];
        #pragma unroll
        for (int i = 0; i < 4; ++i) acc[i] = 0.f;
        #pragma unroll
        for (int qq = 0; qq < E_IN / 4; ++qq) {
            f32x4 v[4];
            #pragma unroll
            for (int i = 0; i < 4; ++i) {
                const int e = ebase + 2 * i + half;
                const f32x4* ew4 = (const f32x4*)(edge_w + (size_t)e * E_IN);
                v[i] = __builtin_nontemporal_load(&ew4[qq]);
            }
            #pragma unroll
            for (int i = 0; i < 4; ++i) {
                acc[i] = fmaf(v[i].x, we3r[4 * qq + 0], acc[i]);
                acc[i] = fmaf(v[i].y, we3r[4 * qq + 1], acc[i]);
                acc[i] = fmaf(v[i].z, we3r[4 * qq + 2], acc[i]);
                acc[i] = fmaf(v[i].w, we3r[4 * qq + 3], acc[i]);
            }
        }

        #pragma unroll
        for (int i = 0; i < 4; ++i) acc[i] += pv[i] + qv[i];

        #pragma unroll
        for (int i = 0; i < 4; ++i) {
            const int e = ebase + 2 * i + half;
            __builtin_nontemporal_store(acc[i], &wout[(size_t)e * E_OUT + ic]);
        }
    }
}

// ---------------------------------------------------------------------------
extern "C" void kernel_launch(void* const* d_in, const int* in_sizes, int n_in,
                              void* d_out, int out_size, void* d_ws, size_t ws_size,
                              hipStream_t stream) {
    const float* h  = (const float*)d_in[0];
    const float* ew = (const float*)d_in[1];
    const float* Wn = (const float*)d_in[2];
    const float* Wa = (const float*)d_in[3];
    const float* Wt = (const float*)d_in[4];
    const float* We = (const float*)d_in[5];
    const int* src  = (const int*)d_in[6];
    const int* dst  = (const int*)d_in[7];

    float* z    = (float*)d_ws;                       // N*64
    float* u    = z + (size_t)N_NODES * D;            // N*64
    float* s1   = u + (size_t)N_NODES * D;            // N
    float* s2   = s1 + N_NODES;                       // N
    float* p    = s2 + N_NODES;                       // N*32
    float* q    = p + (size_t)N_NODES * E_OUT;        // N*32
    int* counts = (int*)(q + (size_t)N_NODES * E_OUT);// N
    int* offs   = counts + N_NODES;                   // N
    int* cursor = offs + N_NODES;                     // N
    int* bsum   = cursor + N_NODES;                   // 256
    int* pe     = bsum + 256;                         // E
    int* ps     = pe + N_EDGES;                       // E
    float* exs  = (float*)(ps + N_EDGES);             // E

    float* hout = (float*)d_out;
    float* wout = hout + (size_t)N_NODES * D;

    hipMemsetAsync(counts, 0, N_NODES * sizeof(int), stream);

    node_a_kernel<<<1024, 256, 0, stream>>>(h, Wn, Wa, Wt, z, u, s1, s2);
    hist_kernel<<<1024, 256, 0, stream>>>(dst, counts);
    scan_sum_kernel<<<N_CHUNKS, 256, 0, stream>>>(counts, bsum);
    scan_top_kernel<<<1, 256, 0, stream>>>(bsum);
    scan_local_kernel<<<N_CHUNKS, 256, 0, stream>>>(counts, bsum, offs, cursor);
    scatter_ex_kernel<<<2048, 256, 0, stream>>>(ew, src, dst, Wa, s1, s2,
                                                cursor, pe, ps, exs);
    edge_a_sorted_kernel<<<2048, 256, 0, stream>>>(ew, pe, ps, exs, offs, counts,
                                                   Wt, We, u, z, hout, p, q);
    edge_b_kernel<<<2048, 256, 0, stream>>>(ew, src, dst, We, p, q, wout);
}

// Round 3
// 973.118 us; speedup vs baseline: 1.3950x; 1.0205x over previous
//
#include <hip/hip_runtime.h>

#define N_NODES 50000
#define N_EDGES 1600000
#define IN_DIM  128
#define D       64      // OUT_DIM
#define E_IN    32
#define E_OUT   32
#define SCAN_CHUNK 256
#define N_CHUNKS ((N_NODES + SCAN_CHUNK - 1) / SCAN_CHUNK)   // 196

typedef __attribute__((ext_vector_type(4))) float f32x4;

__device__ __forceinline__ float rlanef(float v, int l) {
    return __int_as_float(__builtin_amdgcn_readlane(__float_as_int(v), l));
}

// ---------------------------------------------------------------------------
// K1: per-node precompute.  z = h @ W_node  [N,64]
//     s1 = z @ W_attn[:64], s2 = z @ W_attn[64:128]
//     u  = z @ W_tonode[:64]                [N,64]
// ---------------------------------------------------------------------------
__global__ __launch_bounds__(256) void node_a_kernel(
    const float* __restrict__ h, const float* __restrict__ Wn,
    const float* __restrict__ Wa, const float* __restrict__ Wt,
    float* __restrict__ z, float* __restrict__ u,
    float* __restrict__ s1, float* __restrict__ s2)
{
    __shared__ float lWn[IN_DIM * D];   // 32 KB
    __shared__ float lWt1[D * D];       // 16 KB
    __shared__ float lWa[2 * D];
    __shared__ float lh[4][IN_DIM];
    __shared__ float lz[4][D];

    const int tid = threadIdx.x;
    for (int i = tid; i < IN_DIM * D; i += 256) lWn[i] = Wn[i];
    for (int i = tid; i < D * D; i += 256) lWt1[i] = Wt[i];
    if (tid < 2 * D) lWa[tid] = Wa[tid];
    __syncthreads();

    const int wid = tid >> 6;
    const int lane = tid & 63;
    const int nwaves = gridDim.x * 4;

    for (int n = blockIdx.x * 4 + wid; n < N_NODES; n += nwaves) {
        lh[wid][lane]      = h[(size_t)n * IN_DIM + lane];
        lh[wid][lane + 64] = h[(size_t)n * IN_DIM + 64 + lane];

        float acc = 0.f;
        #pragma unroll 8
        for (int k = 0; k < IN_DIM; ++k)
            acc = fmaf(lh[wid][k], lWn[k * D + lane], acc);
        z[(size_t)n * D + lane] = acc;
        lz[wid][lane] = acc;

        float p1 = acc * lWa[lane];
        float p2 = acc * lWa[D + lane];
        #pragma unroll
        for (int off = 32; off > 0; off >>= 1) {
            p1 += __shfl_xor(p1, off, 64);
            p2 += __shfl_xor(p2, off, 64);
        }
        if (lane == 0) { s1[n] = p1; s2[n] = p2; }

        float ua = 0.f;
        #pragma unroll 8
        for (int k = 0; k < D; ++k)
            ua = fmaf(lz[wid][k], lWt1[k * D + lane], ua);
        u[(size_t)n * D + lane] = ua;
    }
}

// ---------------------------------------------------------------------------
// CSR build: histogram -> exclusive scan (3 kernels) -> scatter permutation
// ---------------------------------------------------------------------------
__global__ __launch_bounds__(256) void hist_kernel(
    const int* __restrict__ dst, int* __restrict__ count)
{
    int i = blockIdx.x * 256 + threadIdx.x;
    const int stride = gridDim.x * 256;
    for (; i < N_EDGES; i += stride) atomicAdd(&count[dst[i]], 1);
}

__global__ __launch_bounds__(256) void scan_sum_kernel(
    const int* __restrict__ count, int* __restrict__ bsum)
{
    __shared__ int s[256];
    const int t = threadIdx.x;
    const int idx = blockIdx.x * 256 + t;
    s[t] = (idx < N_NODES) ? count[idx] : 0;
    __syncthreads();
    for (int off = 128; off > 0; off >>= 1) {
        if (t < off) s[t] += s[t + off];
        __syncthreads();
    }
    if (t == 0) bsum[blockIdx.x] = s[0];
}

__global__ __launch_bounds__(256) void scan_top_kernel(int* __restrict__ bsum)
{
    __shared__ int s[256];
    const int t = threadIdx.x;
    const int v = (t < N_CHUNKS) ? bsum[t] : 0;
    s[t] = v;
    __syncthreads();
    for (int off = 1; off < 256; off <<= 1) {
        int x = (t >= off) ? s[t - off] : 0;
        __syncthreads();
        s[t] += x;
        __syncthreads();
    }
    if (t < N_CHUNKS) bsum[t] = s[t] - v;   // exclusive of chunk sums
}

__global__ __launch_bounds__(256) void scan_local_kernel(
    const int* __restrict__ count, const int* __restrict__ bsum,
    int* __restrict__ offsets, int* __restrict__ cursor)
{
    __shared__ int s[256];
    const int t = threadIdx.x;
    const int idx = blockIdx.x * 256 + t;
    const int v = (idx < N_NODES) ? count[idx] : 0;
    s[t] = v;
    __syncthreads();
    for (int off = 1; off < 256; off <<= 1) {
        int x = (t >= off) ? s[t - off] : 0;
        __syncthreads();
        s[t] += x;
        __syncthreads();
    }
    if (idx < N_NODES) {
        int e = bsum[blockIdx.x] + s[t] - v;  // exclusive prefix
        offsets[idx] = e;
        cursor[idx]  = e;
    }
}

// ---------------------------------------------------------------------------
// Scatter + fused attention-logit pass (edge-parallel).
// ---------------------------------------------------------------------------
__global__ __launch_bounds__(256) void scatter_ex_kernel(
    const float* __restrict__ edge_w, const int* __restrict__ src,
    const int* __restrict__ dst, const float* __restrict__ Wa,
    const float* __restrict__ s1, const float* __restrict__ s2,
    int* __restrict__ cursor, int* __restrict__ pe, int* __restrict__ ps,
    float* __restrict__ exs)
{
    float wa[E_IN];
    #pragma unroll
    for (int k = 0; k < E_IN; ++k) wa[k] = Wa[2 * D + k];  // uniform -> SGPRs

    int i = blockIdx.x * 256 + threadIdx.x;
    const int stride = gridDim.x * 256;
    for (; i < N_EDGES; i += stride) {
        const int s = src[i];
        const int d = dst[i];
        float a = s1[s] + s2[d];
        const float4* r4 = (const float4*)(edge_w + (size_t)i * E_IN);
        #pragma unroll
        for (int qq = 0; qq < E_IN / 4; ++qq) {
            float4 v = r4[qq];
            a = fmaf(v.x, wa[4 * qq + 0], a);
            a = fmaf(v.y, wa[4 * qq + 1], a);
            a = fmaf(v.z, wa[4 * qq + 2], a);
            a = fmaf(v.w, wa[4 * qq + 3], a);
        }
        const float lk = (a > 0.f) ? a : 0.1f * a;
        const float ex = __expf(lk);
        const int pos = atomicAdd(&cursor[d], 1);
        pe[pos]  = i;
        ps[pos]  = s;
        exs[pos] = ex;
    }
}

// ---------------------------------------------------------------------------
// K2: sorted edge pass A + fused node finalize.
// Software-pipelined: 4-edge phases, phase i+1's u/ew gathers issued before
// phase i's FMAs consume (ping-pong registers, all static names).
// ---------------------------------------------------------------------------
__global__ __launch_bounds__(256) void edge_a_sorted_kernel(
    const float* __restrict__ edge_w,
    const int* __restrict__ pe, const int* __restrict__ ps,
    const float* __restrict__ exs,
    const int* __restrict__ offsets, const int* __restrict__ count,
    const float* __restrict__ Wt, const float* __restrict__ We,
    const float* __restrict__ u, const float* __restrict__ z,
    float* __restrict__ hout, float* __restrict__ p, float* __restrict__ q)
{
    __shared__ float lWE[D * 64];   // [j][l]: l<32 -> We1[j][l], else We2[j][l-32]
    __shared__ float lh[4][D];
    __shared__ float lrr[4][E_IN];
    const int tid = threadIdx.x;
    for (int i = tid; i < D * 64; i += 256) {
        int j = i >> 6, l = i & 63;
        lWE[i] = We[(j + ((l < 32) ? 0 : D)) * E_OUT + (l & 31)];
    }
    __syncthreads();

    const int wid = tid >> 6, lane = tid & 63;
    const int nwaves = gridDim.x * 4;
    const bool lo = (lane < 32);

    float wt2r[E_IN];
    #pragma unroll
    for (int k = 0; k < E_IN; ++k)
        wt2r[k] = Wt[(D + k) * D + lane];   // lane j holds W_tonode[64+k][j]

    for (int n = blockIdx.x * 4 + wid; n < N_NODES; n += nwaves) {
        const int off = offsets[n];
        const int deg = count[n];
        float g = 0.f, rv = 0.f, denv = 0.f;

        for (int b = 0; b < deg; b += 64) {
            int rem = deg - b; if (rem > 64) rem = 64;
            int eb = 0, sb = 0; float exv = 0.f;
            if (lane < rem) {
                eb  = pe[off + b + lane];
                sb  = ps[off + b + lane];
                exv = exs[off + b + lane];
            }
            denv += exv;
            // lanes >= rem: exv=0, eb=sb=0 -> padded edges contribute 0.
            const int rem8 = (rem + 7) & ~7;

            // ---- prologue: issue phase A = edges [0..3] ----
            int sA0 = __builtin_amdgcn_readlane(sb, 0);
            int sA1 = __builtin_amdgcn_readlane(sb, 1);
            int sA2 = __builtin_amdgcn_readlane(sb, 2);
            int sA3 = __builtin_amdgcn_readlane(sb, 3);
            int eA0 = __builtin_amdgcn_readlane(eb, 0);
            int eA1 = __builtin_amdgcn_readlane(eb, 1);
            int eA2 = __builtin_amdgcn_readlane(eb, 2);
            int eA3 = __builtin_amdgcn_readlane(eb, 3);
            float xA0 = rlanef(exv, 0), xA1 = rlanef(exv, 1);
            float xA2 = rlanef(exv, 2), xA3 = rlanef(exv, 3);
            float uA0 = u[(size_t)sA0 * D + lane];
            float uA1 = u[(size_t)sA1 * D + lane];
            float uA2 = u[(size_t)sA2 * D + lane];
            float uA3 = u[(size_t)sA3 * D + lane];
            float wA0 = edge_w[(size_t)(lo ? eA0 : eA1) * E_IN + (lane & 31)];
            float wA1 = edge_w[(size_t)(lo ? eA2 : eA3) * E_IN + (lane & 31)];
            float xAa = lo ? xA0 : xA1, xAc = lo ? xA2 : xA3;

            for (int i = 0; i < rem8; i += 8) {
                // ---- issue phase B = edges [i+4 .. i+7] ----
                const int jb = i + 4;   // jb+3 <= rem8-1 <= 63
                int sB0 = __builtin_amdgcn_readlane(sb, jb);
                int sB1 = __builtin_amdgcn_readlane(sb, jb + 1);
                int sB2 = __builtin_amdgcn_readlane(sb, jb + 2);
                int sB3 = __builtin_amdgcn_readlane(sb, jb + 3);
                int eB0 = __builtin_amdgcn_readlane(eb, jb);
                int eB1 = __builtin_amdgcn_readlane(eb, jb + 1);
                int eB2 = __builtin_amdgcn_readlane(eb, jb + 2);
                int eB3 = __builtin_amdgcn_readlane(eb, jb + 3);
                float xB0 = rlanef(exv, jb),     xB1 = rlanef(exv, jb + 1);
                float xB2 = rlanef(exv, jb + 2), xB3 = rlanef(exv, jb + 3);
                float uB0 = u[(size_t)sB0 * D + lane];
                float uB1 = u[(size_t)sB1 * D + lane];
                float uB2 = u[(size_t)sB2 * D + lane];
                float uB3 = u[(size_t)sB3 * D + lane];
                float wB0 = edge_w[(size_t)(lo ? eB0 : eB1) * E_IN + (lane & 31)];
                float wB1 = edge_w[(size_t)(lo ? eB2 : eB3) * E_IN + (lane & 31)];
                float xBa = lo ? xB0 : xB1, xBc = lo ? xB2 : xB3;

                // ---- consume phase A ----
                g  = fmaf(xA0, uA0, g);
                g  = fmaf(xA1, uA1, g);
                g  = fmaf(xA2, uA2, g);
                g  = fmaf(xA3, uA3, g);
                rv = fmaf(xAa, wA0, rv);
                rv = fmaf(xAc, wA1, rv);

                // ---- issue next phase A' = edges [i+8 .. i+11] ----
                if (i + 8 < rem8) {     // wave-uniform branch
                    const int ja = i + 8;
                    sA0 = __builtin_amdgcn_readlane(sb, ja);
                    sA1 = __builtin_amdgcn_readlane(sb, ja + 1);
                    sA2 = __builtin_amdgcn_readlane(sb, ja + 2);
                    sA3 = __builtin_amdgcn_readlane(sb, ja + 3);
                    eA0 = __builtin_amdgcn_readlane(eb, ja);
                    eA1 = __builtin_amdgcn_readlane(eb, ja + 1);
                    eA2 = __builtin_amdgcn_readlane(eb, ja + 2);
                    eA3 = __builtin_amdgcn_readlane(eb, ja + 3);
                    xA0 = rlanef(exv, ja);     xA1 = rlanef(exv, ja + 1);
                    xA2 = rlanef(exv, ja + 2); xA3 = rlanef(exv, ja + 3);
                    uA0 = u[(size_t)sA0 * D + lane];
                    uA1 = u[(size_t)sA1 * D + lane];
                    uA2 = u[(size_t)sA2 * D + lane];
                    uA3 = u[(size_t)sA3 * D + lane];
                    wA0 = edge_w[(size_t)(lo ? eA0 : eA1) * E_IN + (lane & 31)];
                    wA1 = edge_w[(size_t)(lo ? eA2 : eA3) * E_IN + (lane & 31)];
                    xAa = lo ? xA0 : xA1; xAc = lo ? xA2 : xA3;
                }

                // ---- consume phase B ----
                g  = fmaf(xB0, uB0, g);
                g  = fmaf(xB1, uB1, g);
                g  = fmaf(xB2, uB2, g);
                g  = fmaf(xB3, uB3, g);
                rv = fmaf(xBa, wB0, rv);
                rv = fmaf(xBc, wB1, rv);
            }
        }

        rv += __shfl_xor(rv, 32, 64);
        if (lane < 32) lrr[wid][lane] = rv;
        #pragma unroll
        for (int o = 32; o > 0; o >>= 1) denv += __shfl_xor(denv, o, 64);

        float acc = g;
        #pragma unroll
        for (int k = 0; k < E_IN; ++k)
            acc = fmaf(lrr[wid][k], wt2r[k], acc);

        const float hv = (deg > 0) ? acc / denv : z[(size_t)n * D + lane];
        hout[(size_t)n * D + lane] = hv;
        lh[wid][lane] = hv;

        float pacc = 0.f;
        #pragma unroll 8
        for (int j = 0; j < D; ++j)
            pacc = fmaf(lh[wid][j], lWE[j * 64 + lane], pacc);

        float* o = (lane < 32) ? p : q;
        o[(size_t)n * E_OUT + (lane & 31)] = pacc;
    }
}

// ---------------------------------------------------------------------------
// K3: edge pass B — 3-deep software pipeline over 8-edge groups.
//   w[e] = p[src[e]] + q[dst[e]] + ew[e] @ We3
// Indices loaded 2 groups ahead; p/q gathers issued 1 group ahead
// (ping-pong A/B register sets); ew streamed nontemporal while the
// next group's gathers are in flight.
// ---------------------------------------------------------------------------
__device__ __forceinline__ void ew_mlp4(const float* __restrict__ edge_w,
                                        int ebase, int half,
                                        const float* we3r, float* acc)
{
    #pragma unroll
    for (int i = 0; i < 4; ++i) acc[i] = 0.f;
    #pragma unroll
    for (int qq = 0; qq < E_IN / 4; ++qq) {
        f32x4 v[4];
        #pragma unroll
        for (int i = 0; i < 4; ++i) {
            const int e = ebase + 2 * i + half;
            const f32x4* ew4 = (const f32x4*)(edge_w + (size_t)e * E_IN);
            v[i] = __builtin_nontemporal_load(&ew4[qq]);
        }
        #pragma unroll
        for (int i = 0; i < 4; ++i) {
            acc[i] = fmaf(v[i].x, we3r[4 * qq + 0], acc[i]);
            acc[i] = fmaf(v[i].y, we3r[4 * qq + 1], acc[i]);
            acc[i] = fmaf(v[i].z, we3r[4 * qq + 2], acc[i]);
            acc[i] = fmaf(v[i].w, we3r[4 * qq + 3], acc[i]);
        }
    }
}

__global__ __launch_bounds__(256) void edge_b_kernel(
    const float* __restrict__ edge_w, const int* __restrict__ src,
    const int* __restrict__ dst, const float* __restrict__ We,
    const float* __restrict__ p, const float* __restrict__ q,
    float* __restrict__ wout)
{
    const int lane = threadIdx.x & 63;
    const int ic   = lane & 31;
    const int half = lane >> 5;
    const int g0   = blockIdx.x * 4 + (threadIdx.x >> 6);
    const int ngroups = N_EDGES / 8;          // 200000 exactly
    const int nw   = gridDim.x * 4;

    float we3r[E_IN];
    #pragma unroll
    for (int k = 0; k < E_IN; ++k) we3r[k] = We[(2 * D + k) * E_OUT + ic];

    int gA = g0;
    if (gA >= ngroups) return;

    // prologue: idx(gA) -> gathers(gA); idx(gB)
    int sA[4], dA[4], sB[4], dB[4];
    #pragma unroll
    for (int i = 0; i < 4; ++i) {
        const int e = gA * 8 + 2 * i + half;
        sA[i] = src[e]; dA[i] = dst[e];
    }
    float pvA[4], qvA[4], pvB[4], qvB[4];
    #pragma unroll
    for (int i = 0; i < 4; ++i) pvA[i] = p[(size_t)sA[i] * E_OUT + ic];
    #pragma unroll
    for (int i = 0; i < 4; ++i) qvA[i] = q[(size_t)dA[i] * E_OUT + ic];

    int gB = gA + nw;
    if (gB < ngroups) {
        #pragma unroll
        for (int i = 0; i < 4; ++i) {
            const int e = gB * 8 + 2 * i + half;
            sB[i] = src[e]; dB[i] = dst[e];
        }
    }

    while (true) {
        // ================= phase A: current group gA =================
        // issue gathers for gB (1 group ahead)
        if (gB < ngroups) {
            #pragma unroll
            for (int i = 0; i < 4; ++i) pvB[i] = p[(size_t)sB[i] * E_OUT + ic];
            #pragma unroll
            for (int i = 0; i < 4; ++i) qvB[i] = q[(size_t)dB[i] * E_OUT + ic];
        }
        // load indices for gC (2 groups ahead) into the A idx slots
        const int gC = gB + nw;
        if (gC < ngroups) {
            #pragma unroll
            for (int i = 0; i < 4; ++i) {
                const int e = gC * 8 + 2 * i + half;
                sA[i] = src[e]; dA[i] = dst[e];
            }
        }
        // stream ew for gA while gathers fly
        {
            float acc[4];
            ew_mlp4(edge_w, gA * 8, half, we3r, acc);
            #pragma unroll
            for (int i = 0; i < 4; ++i) acc[i] += pvA[i] + qvA[i];
            #pragma unroll
            for (int i = 0; i < 4; ++i) {
                const int e = gA * 8 + 2 * i + half;
                __builtin_nontemporal_store(acc[i], &wout[(size_t)e * E_OUT + ic]);
            }
        }
        if (gB >= ngroups) break;

        // ================= phase B: current group gB =================
        if (gC < ngroups) {
            #pragma unroll
            for (int i = 0; i < 4; ++i) pvA[i] = p[(size_t)sA[i] * E_OUT + ic];
            #pragma unroll
            for (int i = 0; i < 4; ++i) qvA[i] = q[(size_t)dA[i] * E_OUT + ic];
        }
        const int gD = gC + nw;
        if (gD < ngroups) {
            #pragma unroll
            for (int i = 0; i < 4; ++i) {
                const int e = gD * 8 + 2 * i + half;
                sB[i] = src[e]; dB[i] = dst[e];
            }
        }
        {
            float acc[4];
            ew_mlp4(edge_w, gB * 8, half, we3r, acc);
            #pragma unroll
            for (int i = 0; i < 4; ++i) acc[i] += pvB[i] + qvB[i];
            #pragma unroll
            for (int i = 0; i < 4; ++i) {
                const int e = gB * 8 + 2 * i + half;
                __builtin_nontemporal_store(acc[i], &wout[(size_t)e * E_OUT + ic]);
            }
        }
        if (gC >= ngroups) break;

        gA = gC; gB = gD;
    }
}

// ---------------------------------------------------------------------------
extern "C" void kernel_launch(void* const* d_in, const int* in_sizes, int n_in,
                              void* d_out, int out_size, void* d_ws, size_t ws_size,
                              hipStream_t stream) {
    const float* h  = (const float*)d_in[0];
    const float* ew = (const float*)d_in[1];
    const float* Wn = (const float*)d_in[2];
    const float* Wa = (const float*)d_in[3];
    const float* Wt = (const float*)d_in[4];
    const float* We = (const float*)d_in[5];
    const int* src  = (const int*)d_in[6];
    const int* dst  = (const int*)d_in[7];

    float* z    = (float*)d_ws;                       // N*64
    float* u    = z + (size_t)N_NODES * D;            // N*64
    float* s1   = u + (size_t)N_NODES * D;            // N
    float* s2   = s1 + N_NODES;                       // N
    float* p    = s2 + N_NODES;                       // N*32
    float* q    = p + (size_t)N_NODES * E_OUT;        // N*32
    int* counts = (int*)(q + (size_t)N_NODES * E_OUT);// N
    int* offs   = counts + N_NODES;                   // N
    int* cursor = offs + N_NODES;                     // N
    int* bsum   = cursor + N_NODES;                   // 256
    int* pe     = bsum + 256;                         // E
    int* ps     = pe + N_EDGES;                       // E
    float* exs  = (float*)(ps + N_EDGES);             // E

    float* hout = (float*)d_out;
    float* wout = hout + (size_t)N_NODES * D;

    hipMemsetAsync(counts, 0, N_NODES * sizeof(int), stream);

    node_a_kernel<<<1024, 256, 0, stream>>>(h, Wn, Wa, Wt, z, u, s1, s2);
    hist_kernel<<<1024, 256, 0, stream>>>(dst, counts);
    scan_sum_kernel<<<N_CHUNKS, 256, 0, stream>>>(counts, bsum);
    scan_top_kernel<<<1, 256, 0, stream>>>(bsum);
    scan_local_kernel<<<N_CHUNKS, 256, 0, stream>>>(counts, bsum, offs, cursor);
    scatter_ex_kernel<<<2048, 256, 0, stream>>>(ew, src, dst, Wa, s1, s2,
                                                cursor, pe, ps, exs);
    edge_a_sorted_kernel<<<2048, 256, 0, stream>>>(ew, pe, ps, exs, offs, counts,
                                                   Wt, We, u, z, hout, p, q);
    edge_b_kernel<<<2048, 256, 0, stream>>>(ew, src, dst, We, p, q, wout);
}